// Round 21
// baseline (608.361 us; speedup 1.0000x reference)
//
#include <hip/hip_runtime.h>
#include <stdint.h>

#define BATCH 8
#define CIN   128
#define HH    192
#define WW    192
#define HW    (HH*WW)       // 36864
#define PXB   576           // (HW/64) pixel-tiles per batch
#define RS    216           // corr LDS row stride (halfs): 432B = 12 banks mod 32

typedef _Float16 half_t;
typedef _Float16 f16x8 __attribute__((ext_vector_type(8)));
typedef _Float16 f16x4 __attribute__((ext_vector_type(4)));
typedef _Float16 f16x2 __attribute__((ext_vector_type(2)));
typedef float    f32x4 __attribute__((ext_vector_type(4)));
typedef float    f32x16 __attribute__((ext_vector_type(16)));
typedef unsigned int u32;

// packed f16 dot2 with f32 accumulate (v_dot2_f32_f16)
__device__ __forceinline__ float DOT2(u32 a, u32 b, float c) {
#if __has_builtin(__builtin_amdgcn_fdot2)
    return __builtin_amdgcn_fdot2(__builtin_bit_cast(f16x2, a),
                                  __builtin_bit_cast(f16x2, b), c, false);
#else
    f16x2 av = __builtin_bit_cast(f16x2, a), bv = __builtin_bit_cast(f16x2, b);
    return c + (float)av[0] * (float)bv[0] + (float)av[1] * (float)bv[1];
#endif
}

// proj smem layout (51.5 KB -> 3 blocks/CU):
#define SMEM_BYTES 52736
#define WSH_OFF    17408
#define MU_OFF     52224

// ln_gemm v3 smem layout (35.5 KB -> 4 blocks/CU, 16 waves):
//   As   [64][136] f16 @ 0      (17408 B)  — persists across nc
//   WSHR @ 17408 (18432 B): Wsh[128][72] f16 (staging, K-half) /
//                           Cst64[64][68] f32 (epilogue chunk) /
//                           redA+redB (LN phase, 8 KB)
//   mu_s/rs_s @ 35840 (512 B)
#define LN_SMEM    36352
#define LN_WSH     17408
#define LN_MU      35840

// ---------------------------------------------------------------------------
// One-shot weight f32 -> f16 conversion into workspace.
// ---------------------------------------------------------------------------
__global__ __launch_bounds__(256)
void wcvt_kernel(const float* __restrict__ qw, const float* __restrict__ kvw,
                 const float* __restrict__ pw, const float* __restrict__ qdw,
                 const float* __restrict__ kvdw, half_t* __restrict__ out)
{
    int q = blockIdx.x * 256 + threadIdx.x;      // float4 index, 34496 total
    if (q >= 34496) return;
    int idx = q * 4;
    const float* src;
    int off;
    if (idx < 32768)       { src = qw;   off = idx; }
    else if (idx < 98304)  { src = kvw;  off = idx - 32768; }
    else if (idx < 131072) { src = pw;   off = idx - 98304; }
    else if (idx < 133376) { src = qdw;  off = idx - 131072; }
    else                   { src = kvdw; off = idx - 133376; }
    float4 v = *(const float4*)&src[off];
    f16x4 o = { (half_t)v.x, (half_t)v.y, (half_t)v.z, (half_t)v.w };
    *(f16x4*)&out[idx] = o;
}

// ---------------------------------------------------------------------------
// Fused LayerNorm(channel) + 1x1 conv GEMM via MFMA 32x32x16 f16, v3:
// K-split Wsh staging (2 x 128x64 halves) + 2-chunk epilogue -> 35.5 KB LDS
// -> 4 blocks/CU (16 waves vs 12). LN stats & MFMA math = round-17 verified.
// ---------------------------------------------------------------------------
template<int OC>
__global__ __launch_bounds__(256)
void ln_gemm_kernel(const float* __restrict__ x,
                    const float* __restrict__ lnw, const float* __restrict__ lnb,
                    const half_t* __restrict__ wf16, const float* __restrict__ wb,
                    half_t* __restrict__ out)
{
    __shared__ __attribute__((aligned(16))) char smem[LN_SMEM];
    half_t (*As)[136]   = (half_t(*)[136])smem;
    half_t (*Wsh)[72]   = (half_t(*)[72]) (smem + LN_WSH);
    float  (*Cst64)[68] = (float (*)[68]) (smem + LN_WSH);
    float* redA = (float*)(smem + LN_WSH);            // [16][64] f32 = 4 KB
    float* redB = (float*)(smem + LN_WSH + 4096);     // [16][64] f32 = 4 KB
    float* mu_s = (float*)(smem + LN_MU);
    float* rs_s = mu_s + 64;

    const int tid  = threadIdx.x;
    const int l    = tid & 63;
    const int w    = tid >> 6;
    const int lrow = l & 31;
    const int lk   = (l >> 5) * 8;

    const long p0  = (long)blockIdx.x * 64;
    const int  b   = (int)(p0 / HW);
    const int  hw0 = (int)(p0 - (long)b * HW);

    // ---- LN stats (vectorized) ----
    const int pxq = tid & 15;          // 4 px (float4)
    const int cg  = tid >> 4;          // 16 groups x 8 ch
    const float* xb = x + (size_t)b * CIN * HW + hw0 + pxq * 4;
    float4 vals[8];
    float4 s1 = {0.f,0.f,0.f,0.f}, s2 = {0.f,0.f,0.f,0.f};
#pragma unroll
    for (int j = 0; j < 8; ++j) {
        float4 vv = *(const float4*)&xb[(size_t)(cg * 8 + j) * HW];
        vals[j] = vv;
        s1.x += vv.x; s1.y += vv.y; s1.z += vv.z; s1.w += vv.w;
        s2.x += vv.x*vv.x; s2.y += vv.y*vv.y; s2.z += vv.z*vv.z; s2.w += vv.w*vv.w;
    }
    redA[cg * 64 + pxq * 4 + 0] = s1.x; redB[cg * 64 + pxq * 4 + 0] = s2.x;
    redA[cg * 64 + pxq * 4 + 1] = s1.y; redB[cg * 64 + pxq * 4 + 1] = s2.y;
    redA[cg * 64 + pxq * 4 + 2] = s1.z; redB[cg * 64 + pxq * 4 + 2] = s2.z;
    redA[cg * 64 + pxq * 4 + 3] = s1.w; redB[cg * 64 + pxq * 4 + 3] = s2.w;
    __syncthreads();
    if (tid < 64) {
        float su = 0.f, sq = 0.f;
#pragma unroll
        for (int c = 0; c < 16; ++c) { su += redA[c * 64 + tid]; sq += redB[c * 64 + tid]; }
        float mu  = su * (1.f / 128.f);
        float var = sq * (1.f / 128.f) - mu * mu;
        mu_s[tid] = mu;
        rs_s[tid] = rsqrtf(var + 1e-5f);
    }
    __syncthreads();
    {
        float mu_a[4], rs_a[4];
#pragma unroll
        for (int k = 0; k < 4; ++k) { mu_a[k] = mu_s[pxq * 4 + k]; rs_a[k] = rs_s[pxq * 4 + k]; }
#pragma unroll
        for (int k = 0; k < 4; ++k) {
            f16x8 o;
#pragma unroll
            for (int j = 0; j < 8; ++j) {
                int c = cg * 8 + j;
                float v = (k == 0) ? vals[j].x : (k == 1) ? vals[j].y
                        : (k == 2) ? vals[j].z : vals[j].w;
                o[j] = (half_t)((v - mu_a[k]) * rs_a[k] * lnw[c] + lnb[c]);
            }
            *(f16x8*)&As[pxq * 4 + k][cg * 8] = o;
        }
    }

    for (int nc = 0; nc < OC / 128; ++nc) {
        const int n0 = nc * 128;
        f32x16 acc0, acc1;
#pragma unroll
        for (int i = 0; i < 16; ++i) { acc0[i] = 0.f; acc1[i] = 0.f; }

#pragma unroll
        for (int kh = 0; kh < 2; ++kh) {
            if (nc || kh) __syncthreads();    // prior Wsh/Cst64 readers done
            // stage 128 rows x 64 cols of this K-half: 1024 f16x8, 4/thread
#pragma unroll
            for (int i = 0; i < 4; ++i) {
                int f  = i * 256 + tid;
                int n  = f >> 3;
                int xh = (f & 7) * 8;
                *(f16x8*)&Wsh[n][xh] =
                    *(const f16x8*)&wf16[(size_t)(n0 + n) * CIN + kh * 64 + xh];
            }
            __syncthreads();

            f16x8 af[4];
#pragma unroll
            for (int kk = 0; kk < 4; ++kk)
                af[kk] = *(const f16x8*)&Wsh[w * 32 + lrow][kk * 16 + lk];
#pragma unroll
            for (int kk = 0; kk < 4; ++kk) {
                f16x8 b0 = *(const f16x8*)&As[lrow][kh * 64 + kk * 16 + lk];
                f16x8 b1 = *(const f16x8*)&As[32 + lrow][kh * 64 + kk * 16 + lk];
                acc0 = __builtin_amdgcn_mfma_f32_32x32x16_f16(af[kk], b0, acc0, 0, 0, 0);
                acc1 = __builtin_amdgcn_mfma_f32_32x32x16_f16(af[kk], b1, acc1, 0, 0, 0);
            }
        }
        __syncthreads();                      // mfma Wsh reads done

        // epilogue: 2 chunks of 64 oc rows through Cst64
#pragma unroll
        for (int ck = 0; ck < 2; ++ck) {
            if (ck) __syncthreads();          // chunk-0 store reads done
            if ((w >> 1) == ck) {             // waves 2ck, 2ck+1 own these rows
#pragma unroll
                for (int r = 0; r < 16; ++r) {
                    int ocl = (w & 1) * 32 + (r & 3) + 8 * (r >> 2) + 4 * (l >> 5);
                    Cst64[ocl][lrow]      = acc0[r];
                    Cst64[ocl][32 + lrow] = acc1[r];
                }
            }
            __syncthreads();
#pragma unroll
            for (int i = 0; i < 2; ++i) {
                int idx = i * 256 + tid;      // 512 f16x8 stores
                int ocl = idx >> 3;
                int pxg = idx & 7;
                const float4 a = *(const float4*)&Cst64[ocl][pxg * 8];
                const float4 c = *(const float4*)&Cst64[ocl][pxg * 8 + 4];
                int oc = n0 + ck * 64 + ocl;
                float bias = wb[oc];
                f16x8 o = { (half_t)(a.x + bias), (half_t)(a.y + bias),
                            (half_t)(a.z + bias), (half_t)(a.w + bias),
                            (half_t)(c.x + bias), (half_t)(c.y + bias),
                            (half_t)(c.z + bias), (half_t)(c.w + bias) };
                *(f16x8*)&out[((size_t)b * OC + oc) * HW + hw0 + pxg * 8] = o;
            }
        }
    }
}

// ---------------------------------------------------------------------------
// Strip-based fused dwconv(q,k,v) + per-patch 8x8 circular conv, v6 (CH=1,
// 19.9 KB LDS, 8 blocks/CU). Round-20 verified. UNCHANGED.
// ---------------------------------------------------------------------------
__global__ __launch_bounds__(256)
void corr_strip_kernel(const half_t* __restrict__ q1, const half_t* __restrict__ kv1,
                       const half_t* __restrict__ qdw16, const float* __restrict__ qb,
                       const half_t* __restrict__ kdw16, const float* __restrict__ kb,
                       half_t* __restrict__ corr, half_t* __restrict__ vd)
{
    __shared__ __attribute__((aligned(16))) half_t raw[3][10][RS];
    __shared__ __attribute__((aligned(16))) half_t qd[8][RS];
    __shared__ __attribute__((aligned(16))) half_t krev[8][RS];

    const int bid = blockIdx.x;
    const int c0  = bid & 255;          // channel
    const int ph  = (bid >> 8) % 24;
    const int lb  = (bid >> 8) / 24;
    const int tid = threadIdx.x;

    // ---- zero the column-halo slots ----
    if (tid < 60) {
        int side = tid & 1;
        int row  = (tid >> 1) % 10;
        int a    = tid / 20;            // 0..2
        f16x8 z = {};
        *(f16x8*)&raw[a][row][side ? 200 : 0] = z;
    }

    // ---- stage A: coalesced strip loads (720 vector loads) ----
    for (int i = 0; i < 3; ++i) {
        int idx = tid + 256 * i;
        if (idx >= 720) break;
        int vec = idx % 24;
        int row = (idx / 24) % 10;
        int a   = idx / 240;            // 0..2
        int gh  = ph * 8 - 1 + row;
        f16x8 v = {};
        if (gh >= 0 && gh < HH) {
            const half_t* src;
            if (a == 0)      src = q1  + ((size_t)lb * 256 + c0) * HW;
            else if (a == 1) src = kv1 + ((size_t)lb * 512 + c0) * HW;
            else             src = kv1 + ((size_t)lb * 512 + 256 + c0) * HW;
            v = *(const f16x8*)&src[(size_t)gh * WW + vec * 8];
        }
        *(f16x8*)&raw[a][row][8 + vec * 8] = v;
    }
    __syncthreads();

    // ---- stage B: dwconv via dot2; u-fastest mapping, 288 units ----
    for (int i = 0; i < 2; ++i) {
        int unit = tid + 256 * i;
        if (unit >= 288) break;
        int u   = unit & 7;
        int xg2 = (unit >> 3) % 12;
        int a   = unit / 96;            // 0..2
        const half_t (*rw)[RS] = raw[a];
        const half_t* wt;
        float bias;
        if (a == 0)      { wt = qdw16 + (size_t)c0 * 9;         bias = qb[c0]; }
        else if (a == 1) { wt = kdw16 + (size_t)c0 * 9;         bias = kb[c0]; }
        else             { wt = kdw16 + (size_t)(256 + c0) * 9; bias = kb[256 + c0]; }
        u32 w01[3], w2z[3];
#pragma unroll
        for (int dy = 0; dy < 3; ++dy) {
            u32 a0 = (u32)__builtin_bit_cast(unsigned short, wt[dy * 3 + 0]);
            u32 a1 = (u32)__builtin_bit_cast(unsigned short, wt[dy * 3 + 1]);
            u32 a2 = (u32)__builtin_bit_cast(unsigned short, wt[dy * 3 + 2]);
            w01[dy] = a0 | (a1 << 16);
            w2z[dy] = a2;
        }
        const int x0 = xg2 * 16;
        float acc[16];
#pragma unroll
        for (int xx = 0; xx < 16; ++xx) acc[xx] = bias;
#pragma unroll
        for (int dy = 0; dy < 3; ++dy) {
            const half_t* rowp = &rw[u + dy][x0];
            uint4 c0v = *(const uint4*)(rowp);
            uint4 c1v = *(const uint4*)(rowp + 8);
            uint4 c2v = *(const uint4*)(rowp + 16);
            uint4 c3v = *(const uint4*)(rowp + 24);
            u32 H[13] = {c0v.x,c0v.y,c0v.z,c0v.w, c1v.x,c1v.y,c1v.z,c1v.w,
                         c2v.x,c2v.y,c2v.z,c2v.w, c3v.x};
            u32 A[12];
#pragma unroll
            for (int m = 3; m < 12; ++m) A[m] = (H[m] >> 16) | (H[m + 1] << 16);
#pragma unroll
            for (int xx = 0; xx < 16; ++xx) {
                u32 p01 = (xx & 1) ? H[(7 + xx) >> 1] : A[3 + (xx >> 1)];
                u32 p2  = (xx & 1) ? H[(9 + xx) >> 1] : A[4 + (xx >> 1)];
                acc[xx] = DOT2(p01, w01[dy], acc[xx]);
                acc[xx] = DOT2(p2,  w2z[dy], acc[xx]);
            }
        }
        f16x8 o0, o1;
#pragma unroll
        for (int xx = 0; xx < 8; ++xx) { o0[xx] = (half_t)acc[xx]; o1[xx] = (half_t)acc[8 + xx]; }
        if (a == 0) {
            *(f16x8*)&qd[u][x0]     = o0;
            *(f16x8*)&qd[u][x0 + 8] = o1;
        } else if (a == 1) {
            f16x8 r0v, r1v;
            r0v[0] = (half_t)acc[0];
            r1v[0] = (half_t)acc[8];
#pragma unroll
            for (int j = 1; j < 8; ++j) {
                r0v[j] = (half_t)acc[8 - j];
                r1v[j] = (half_t)acc[16 - j];
            }
            *(f16x8*)&krev[u][x0]     = r0v;
            *(f16x8*)&krev[u][x0 + 8] = r1v;
        } else {
            half_t* dst = &vd[((size_t)lb * 256 + c0) * HW + (size_t)(ph * 8 + u) * WW + x0];
            *(f16x8*)dst       = o0;
            *(f16x8*)(dst + 8) = o1;
        }
    }
    __syncthreads();

    // ---- stage C: circular conv via dot2, 192 units (tid<192) ----
    if (tid < 192) {
        int pw = tid >> 3;
        int u  = tid & 7;
        float acc[8];
#pragma unroll
        for (int v = 0; v < 8; ++v) acc[v] = 0.f;
#pragma unroll
        for (int s = 0; s < 8; ++s) {
            int r = (u - s) & 7;
            uint4 q4 = *(const uint4*)&qd[s][pw * 8];
            uint4 k4 = *(const uint4*)&krev[r][pw * 8];
            u32 Q[4] = {q4.x, q4.y, q4.z, q4.w};
            u32 K[4] = {k4.x, k4.y, k4.z, k4.w};
            u32 S[4];
#pragma unroll
            for (int m = 0; m < 4; ++m) S[m] = (K[m] >> 16) | (K[(m + 1) & 3] << 16);
#pragma unroll
            for (int v = 0; v < 8; ++v) {
                const int o = 8 - v;
#pragma unroll
                for (int tt = 0; tt < 4; ++tt) {
                    u32 pr = (o & 1) ? S[(((o - 1) >> 1) + tt) & 3]
                                     : K[((o >> 1) + tt) & 3];
                    acc[v] = DOT2(Q[tt], pr, acc[v]);
                }
            }
        }
        f16x8 ov;
#pragma unroll
        for (int v = 0; v < 8; ++v) ov[v] = (half_t)acc[v];
        *(f16x8*)&corr[((size_t)lb * 256 + c0) * HW + (size_t)(ph * 8 + u) * WW + pw * 8] = ov;
    }
}

// ---------------------------------------------------------------------------
// Fused LN(corr)*vd + 1x1 proj GEMM via MFMA 32x32x16 -> f32 out.
// Round-16/17 verified form. UNCHANGED.
// ---------------------------------------------------------------------------
__global__ __launch_bounds__(256)
void proj_kernel(const half_t* __restrict__ corr, const half_t* __restrict__ vd,
                 const float* __restrict__ lnw, const float* __restrict__ lnb,
                 const half_t* __restrict__ wp16, const float* __restrict__ wb,
                 float* __restrict__ out)
{
    __shared__ __attribute__((aligned(16))) char smem[SMEM_BYTES];
    half_t (*As)[136]  = (half_t(*)[136])smem;
    half_t (*Wsh)[136] = (half_t(*)[136])(smem + WSH_OFF);
    float  (*Cst)[68]  = (float (*)[68]) (smem + WSH_OFF);
    float* redA = (float*)(smem + WSH_OFF);           // [32][64] f32 = 8 KB
    float* redB = (float*)(smem + WSH_OFF + 8192);    // [32][64] f32 = 8 KB
    float* mu_s = (float*)(smem + MU_OFF);
    float* rs_s = mu_s + 64;

    const int tid  = threadIdx.x;
    const int l    = tid & 63;
    const int w    = tid >> 6;
    const int lrow = l & 31;
    const int lk   = (l >> 5) * 8;

    const long p0  = (long)blockIdx.x * 64;
    const int  lb  = (int)(p0 / HW);
    const int  hw0 = (int)(p0 - (long)lb * HW);

    // ---- LN stats (vectorized, corr cached in f16x8 registers) ----
    const int pxq8 = tid & 7;          // 8 px (f16x8)
    const int cg   = tid >> 3;         // 32 groups x 8 ch
    const half_t* cb = corr + (size_t)lb * 256 * HW + hw0 + pxq8 * 8;
    const half_t* vb = vd   + (size_t)lb * 256 * HW + hw0 + pxq8 * 8;

    f16x8 cpk[8];
    float s1[8], s2[8];
#pragma unroll
    for (int p = 0; p < 8; ++p) { s1[p] = 0.f; s2[p] = 0.f; }
#pragma unroll
    for (int j = 0; j < 8; ++j) {
        cpk[j] = *(const f16x8*)&cb[(size_t)(cg * 8 + j) * HW];
#pragma unroll
        for (int p = 0; p < 8; ++p) {
            float f = (float)cpk[j][p];
            s1[p] += f; s2[p] += f * f;
        }
    }
#pragma unroll
    for (int p = 0; p < 8; ++p) {
        redA[cg * 64 + pxq8 * 8 + p] = s1[p];
        redB[cg * 64 + pxq8 * 8 + p] = s2[p];
    }
    __syncthreads();
    if (tid < 64) {
        float su = 0.f, sq = 0.f;
#pragma unroll
        for (int c = 0; c < 32; ++c) { su += redA[c * 64 + tid]; sq += redB[c * 64 + tid]; }
        float mu  = su * (1.f / 256.f);
        float var = sq * (1.f / 256.f) - mu * mu;
        mu_s[tid] = mu;
        rs_s[tid] = rsqrtf(var + 1e-5f);
    }
    __syncthreads();

    f32x16 acc0, acc1;
#pragma unroll
    for (int i = 0; i < 16; ++i) { acc0[i] = 0.f; acc1[i] = 0.f; }

    for (int kc = 0; kc < 2; ++kc) {
        if (kc) __syncthreads();          // prior kc MFMA readers done with As
        if ((cg >> 4) == kc) {
            const int cgl = cg & 15;      // local channel group (0..15)
            float mu8[8], rs8[8];
#pragma unroll
            for (int p = 0; p < 8; ++p) {
                mu8[p] = mu_s[pxq8 * 8 + p];
                rs8[p] = rs_s[pxq8 * 8 + p];
            }
            f16x8 vvv[8];
            float lw[8], lbv[8];
#pragma unroll
            for (int j = 0; j < 8; ++j) {
                int c = kc * 128 + cgl * 8 + j;   // == cg*8 + j
                vvv[j] = *(const f16x8*)&vb[(size_t)c * HW];
                lw[j]  = lnw[c]; lbv[j] = lnb[c];
            }
#pragma unroll
            for (int p = 0; p < 8; ++p) {
                f16x8 o;
#pragma unroll
                for (int j = 0; j < 8; ++j) {
                    float cf = (float)cpk[j][p];
                    o[j] = (half_t)(((cf - mu8[p]) * rs8[p] * lw[j] + lbv[j]) * (float)vvv[j][p]);
                }
                *(f16x8*)&As[pxq8 * 8 + p][cgl * 8] = o;
            }
        }
#pragma unroll
        for (int i = 0; i < 8; ++i) {
            int f  = i * 256 + tid;
            int n  = f >> 4;
            int xh = (f & 15) * 8;
            *(f16x8*)&Wsh[n][xh] = *(const f16x8*)&wp16[(size_t)n * 256 + kc * 128 + xh];
        }
        __syncthreads();

        f16x8 af[8];
#pragma unroll
        for (int kk = 0; kk < 8; ++kk)
            af[kk] = *(const f16x8*)&Wsh[w * 32 + lrow][kk * 16 + lk];
#pragma unroll
        for (int kk = 0; kk < 8; ++kk) {
            f16x8 b0 = *(const f16x8*)&As[lrow][kk * 16 + lk];
            f16x8 b1 = *(const f16x8*)&As[32 + lrow][kk * 16 + lk];
            acc0 = __builtin_amdgcn_mfma_f32_32x32x16_f16(af[kk], b0, acc0, 0, 0, 0);
            acc1 = __builtin_amdgcn_mfma_f32_32x32x16_f16(af[kk], b1, acc1, 0, 0, 0);
        }
    }
    __syncthreads();

#pragma unroll
    for (int r = 0; r < 16; ++r) {
        int oc = w * 32 + (r & 3) + 8 * (r >> 2) + 4 * (l >> 5);
        Cst[oc][lrow]      = acc0[r];
        Cst[oc][32 + lrow] = acc1[r];
    }
    __syncthreads();

#pragma unroll
    for (int i = 0; i < 8; ++i) {
        int idx = i * 256 + tid;          // 2048 float4 stores
        int oc  = idx >> 4;
        int pxq = idx & 15;
        float4 a = *(const float4*)&Cst[oc][pxq * 4];
        float bias = wb[oc];
        a.x += bias; a.y += bias; a.z += bias; a.w += bias;
        *(float4*)&out[((size_t)lb * 128 + oc) * HW + hw0 + pxq * 4] = a;
    }
}

// ---------------------------------------------------------------------------
extern "C" void kernel_launch(void* const* d_in, const int* in_sizes, int n_in,
                              void* d_out, int out_size, void* d_ws, size_t ws_size,
                              hipStream_t stream)
{
    const float* x        = (const float*)d_in[0];
    const float* evt      = (const float*)d_in[1];
    const float* ln_img_w = (const float*)d_in[2];
    const float* ln_img_b = (const float*)d_in[3];
    const float* ln_evt_w = (const float*)d_in[4];
    const float* ln_evt_b = (const float*)d_in[5];
    const float* q_w      = (const float*)d_in[6];
    const float* q_b      = (const float*)d_in[7];
    const float* q_dw_w   = (const float*)d_in[8];
    const float* q_dw_b   = (const float*)d_in[9];
    const float* kv_w     = (const float*)d_in[10];
    const float* kv_b     = (const float*)d_in[11];
    const float* kv_dw_w  = (const float*)d_in[12];
    const float* kv_dw_b  = (const float*)d_in[13];
    const float* ln_corr_w= (const float*)d_in[14];
    const float* ln_corr_b= (const float*)d_in[15];
    const float* proj_w   = (const float*)d_in[16];
    const float* proj_b   = (const float*)d_in[17];
    float* out = (float*)d_out;

    // f16 weight cache at the tail of ws (137984 halfs = 276 KB)
    const size_t wtail = (ws_size - 278528) & ~(size_t)255;
    half_t* wf    = (half_t*)((char*)d_ws + wtail);
    half_t* wq16  = wf;             // 256x128
    half_t* wkv16 = wf + 32768;     // 512x128
    half_t* wp16  = wf + 98304;     // 128x256
    half_t* qdw16 = wf + 131072;    // 256x9
    half_t* kdw16 = wf + 133376;    // 512x9

    const size_t per_b = (size_t)(256 + 512 + 256 + 256) * HW * sizeof(half_t); // 94.4 MB
    int PB = 1;
    if      (wtail >= 8 * per_b) PB = 8;
    else if (wtail >= 4 * per_b) PB = 4;
    else if (wtail >= 2 * per_b) PB = 2;

    half_t* q1   = (half_t*)d_ws;
    half_t* kv1  = q1  + (size_t)PB * 256 * HW;
    half_t* vd   = kv1 + (size_t)PB * 512 * HW;
    half_t* corr = vd  + (size_t)PB * 256 * HW;

    dim3 blk(256);
    wcvt_kernel<<<135, blk, 0, stream>>>(q_w, kv_w, proj_w, q_dw_w, kv_dw_w, wf);

    for (int b0 = 0; b0 < BATCH; b0 += PB) {
        int nb = PB;
        ln_gemm_kernel<256><<<nb * PXB, blk, 0, stream>>>(
            x + (size_t)b0 * CIN * HW, ln_img_w, ln_img_b, wq16, q_b, q1);
        ln_gemm_kernel<512><<<nb * PXB, blk, 0, stream>>>(
            evt + (size_t)b0 * CIN * HW, ln_evt_w, ln_evt_b, wkv16, kv_b, kv1);
        corr_strip_kernel<<<nb * 24 * 256, blk, 0, stream>>>(
            q1, kv1, qdw16, q_dw_b, kdw16, kv_dw_b, corr, vd);
        proj_kernel<<<nb * PXB, blk, 0, stream>>>(
            corr, vd, ln_corr_w, ln_corr_b, wp16, proj_b,
            out + (size_t)b0 * 128 * HW);
    }
}

// Round 22
// 600.750 us; speedup vs baseline: 1.0127x; 1.0127x over previous
//
#include <hip/hip_runtime.h>
#include <stdint.h>

#define BATCH 8
#define CIN   128
#define HH    192
#define WW    192
#define HW    (HH*WW)       // 36864
#define PXB   576           // (HW/64) pixel-tiles per batch
#define RS    216           // corr LDS row stride (halfs): 432B = 12 banks mod 32

typedef _Float16 half_t;
typedef _Float16 f16x8 __attribute__((ext_vector_type(8)));
typedef _Float16 f16x4 __attribute__((ext_vector_type(4)));
typedef _Float16 f16x2 __attribute__((ext_vector_type(2)));
typedef float    f32x4 __attribute__((ext_vector_type(4)));
typedef float    f32x16 __attribute__((ext_vector_type(16)));
typedef unsigned int u32;

// packed f16 dot2 with f32 accumulate (v_dot2_f32_f16)
__device__ __forceinline__ float DOT2(u32 a, u32 b, float c) {
#if __has_builtin(__builtin_amdgcn_fdot2)
    return __builtin_amdgcn_fdot2(__builtin_bit_cast(f16x2, a),
                                  __builtin_bit_cast(f16x2, b), c, false);
#else
    f16x2 av = __builtin_bit_cast(f16x2, a), bv = __builtin_bit_cast(f16x2, b);
    return c + (float)av[0] * (float)bv[0] + (float)av[1] * (float)bv[1];
#endif
}

// shared-memory layout for the MFMA kernels (51.5 KB -> 3 blocks/CU):
#define SMEM_BYTES 52736
#define WSH_OFF    17408
#define MU_OFF     52224

// ---------------------------------------------------------------------------
// One-shot weight f32 -> f16 conversion into workspace.
// ---------------------------------------------------------------------------
__global__ __launch_bounds__(256)
void wcvt_kernel(const float* __restrict__ qw, const float* __restrict__ kvw,
                 const float* __restrict__ pw, const float* __restrict__ qdw,
                 const float* __restrict__ kvdw, half_t* __restrict__ out)
{
    int q = blockIdx.x * 256 + threadIdx.x;      // float4 index, 34496 total
    if (q >= 34496) return;
    int idx = q * 4;
    const float* src;
    int off;
    if (idx < 32768)       { src = qw;   off = idx; }
    else if (idx < 98304)  { src = kvw;  off = idx - 32768; }
    else if (idx < 131072) { src = pw;   off = idx - 98304; }
    else if (idx < 133376) { src = qdw;  off = idx - 131072; }
    else                   { src = kvdw; off = idx - 133376; }
    float4 v = *(const float4*)&src[off];
    f16x4 o = { (half_t)v.x, (half_t)v.y, (half_t)v.z, (half_t)v.w };
    *(f16x4*)&out[idx] = o;
}

// ---------------------------------------------------------------------------
// Fused LayerNorm(channel) + 1x1 conv GEMM via MFMA 32x32x16 f16.
// Round-17/20 verified form (vectorized LN stats; single-stage Wsh;
// Cst transpose epilogue). K-split variant (round 21) was neutral-negative:
// barrier cost offset the occupancy gain.
// ---------------------------------------------------------------------------
template<int OC>
__global__ __launch_bounds__(256)
void ln_gemm_kernel(const float* __restrict__ x,
                    const float* __restrict__ lnw, const float* __restrict__ lnb,
                    const half_t* __restrict__ wf16, const float* __restrict__ wb,
                    half_t* __restrict__ out)
{
    __shared__ __attribute__((aligned(16))) char smem[SMEM_BYTES];
    half_t (*As)[136]  = (half_t(*)[136])smem;
    half_t (*Wsh)[136] = (half_t(*)[136])(smem + WSH_OFF);
    float  (*Cst)[68]  = (float (*)[68]) (smem + WSH_OFF);
    float* redA = (float*)(smem + WSH_OFF);           // [16][64] f32 = 4 KB
    float* redB = (float*)(smem + WSH_OFF + 4096);    // [16][64] f32 = 4 KB
    float* mu_s = (float*)(smem + MU_OFF);
    float* rs_s = mu_s + 64;

    const int tid  = threadIdx.x;
    const int l    = tid & 63;
    const int w    = tid >> 6;
    const int lrow = l & 31;
    const int lk   = (l >> 5) * 8;

    const long p0  = (long)blockIdx.x * 64;
    const int  b   = (int)(p0 / HW);
    const int  hw0 = (int)(p0 - (long)b * HW);

    // ---- LN stats (vectorized) ----
    const int pxq = tid & 15;          // 4 px (float4)
    const int cg  = tid >> 4;          // 16 groups x 8 ch
    const float* xb = x + (size_t)b * CIN * HW + hw0 + pxq * 4;
    float4 vals[8];
    float4 s1 = {0.f,0.f,0.f,0.f}, s2 = {0.f,0.f,0.f,0.f};
#pragma unroll
    for (int j = 0; j < 8; ++j) {
        float4 vv = *(const float4*)&xb[(size_t)(cg * 8 + j) * HW];
        vals[j] = vv;
        s1.x += vv.x; s1.y += vv.y; s1.z += vv.z; s1.w += vv.w;
        s2.x += vv.x*vv.x; s2.y += vv.y*vv.y; s2.z += vv.z*vv.z; s2.w += vv.w*vv.w;
    }
    redA[cg * 64 + pxq * 4 + 0] = s1.x; redB[cg * 64 + pxq * 4 + 0] = s2.x;
    redA[cg * 64 + pxq * 4 + 1] = s1.y; redB[cg * 64 + pxq * 4 + 1] = s2.y;
    redA[cg * 64 + pxq * 4 + 2] = s1.z; redB[cg * 64 + pxq * 4 + 2] = s2.z;
    redA[cg * 64 + pxq * 4 + 3] = s1.w; redB[cg * 64 + pxq * 4 + 3] = s2.w;
    __syncthreads();
    if (tid < 64) {
        float su = 0.f, sq = 0.f;
#pragma unroll
        for (int c = 0; c < 16; ++c) { su += redA[c * 64 + tid]; sq += redB[c * 64 + tid]; }
        float mu  = su * (1.f / 128.f);
        float var = sq * (1.f / 128.f) - mu * mu;
        mu_s[tid] = mu;
        rs_s[tid] = rsqrtf(var + 1e-5f);
    }
    __syncthreads();
    {
        float mu_a[4], rs_a[4];
#pragma unroll
        for (int k = 0; k < 4; ++k) { mu_a[k] = mu_s[pxq * 4 + k]; rs_a[k] = rs_s[pxq * 4 + k]; }
#pragma unroll
        for (int k = 0; k < 4; ++k) {
            f16x8 o;
#pragma unroll
            for (int j = 0; j < 8; ++j) {
                int c = cg * 8 + j;
                float v = (k == 0) ? vals[j].x : (k == 1) ? vals[j].y
                        : (k == 2) ? vals[j].z : vals[j].w;
                o[j] = (half_t)((v - mu_a[k]) * rs_a[k] * lnw[c] + lnb[c]);
            }
            *(f16x8*)&As[pxq * 4 + k][cg * 8] = o;
        }
    }

    for (int nc = 0; nc < OC / 128; ++nc) {
        const int n0 = nc * 128;
        if (nc) __syncthreads();          // prev epilogue readers done
#pragma unroll
        for (int i = 0; i < 8; ++i) {
            int f  = i * 256 + tid;       // 2048 b128 loads
            int n  = f >> 4;
            int xh = (f & 15) * 8;
            *(f16x8*)&Wsh[n][xh] = *(const f16x8*)&wf16[(size_t)(n0 + n) * CIN + xh];
        }
        __syncthreads();

        f16x8 af[8];
#pragma unroll
        for (int kk = 0; kk < 8; ++kk)
            af[kk] = *(const f16x8*)&Wsh[w * 32 + lrow][kk * 16 + lk];

        f32x16 acc0, acc1;
#pragma unroll
        for (int i = 0; i < 16; ++i) { acc0[i] = 0.f; acc1[i] = 0.f; }
#pragma unroll
        for (int kk = 0; kk < 8; ++kk) {
            f16x8 b0 = *(const f16x8*)&As[lrow][kk * 16 + lk];
            f16x8 b1 = *(const f16x8*)&As[32 + lrow][kk * 16 + lk];
            acc0 = __builtin_amdgcn_mfma_f32_32x32x16_f16(af[kk], b0, acc0, 0, 0, 0);
            acc1 = __builtin_amdgcn_mfma_f32_32x32x16_f16(af[kk], b1, acc1, 0, 0, 0);
        }
        __syncthreads();                  // all waves done with Wsh/As reads

        // transpose: D[row=oc][col=px], row=(r&3)+8*(r>>2)+4*(l>>5), col=lrow
#pragma unroll
        for (int r = 0; r < 16; ++r) {
            int oc = w * 32 + (r & 3) + 8 * (r >> 2) + 4 * (l >> 5);
            Cst[oc][lrow]      = acc0[r];
            Cst[oc][32 + lrow] = acc1[r];
        }
        __syncthreads();

#pragma unroll
        for (int i = 0; i < 4; ++i) {
            int idx = i * 256 + tid;      // 1024 b128 stores
            int oc  = idx >> 3;
            int pxg = idx & 7;
            const float4 a = *(const float4*)&Cst[oc][pxg * 8];
            const float4 c = *(const float4*)&Cst[oc][pxg * 8 + 4];
            float bias = wb[n0 + oc];
            f16x8 o = { (half_t)(a.x + bias), (half_t)(a.y + bias),
                        (half_t)(a.z + bias), (half_t)(a.w + bias),
                        (half_t)(c.x + bias), (half_t)(c.y + bias),
                        (half_t)(c.z + bias), (half_t)(c.w + bias) };
            *(f16x8*)&out[((size_t)b * OC + n0 + oc) * HW + hw0 + pxg * 8] = o;
        }
    }
}

// ---------------------------------------------------------------------------
// Strip-based fused dwconv(q,k,v) + per-patch 8x8 circular conv, v6 (CH=1,
// 19.9 KB LDS, 8 blocks/CU, 79% occupancy). Round-20 verified.
// ---------------------------------------------------------------------------
__global__ __launch_bounds__(256)
void corr_strip_kernel(const half_t* __restrict__ q1, const half_t* __restrict__ kv1,
                       const half_t* __restrict__ qdw16, const float* __restrict__ qb,
                       const half_t* __restrict__ kdw16, const float* __restrict__ kb,
                       half_t* __restrict__ corr, half_t* __restrict__ vd)
{
    __shared__ __attribute__((aligned(16))) half_t raw[3][10][RS];
    __shared__ __attribute__((aligned(16))) half_t qd[8][RS];
    __shared__ __attribute__((aligned(16))) half_t krev[8][RS];

    const int bid = blockIdx.x;
    const int c0  = bid & 255;          // channel
    const int ph  = (bid >> 8) % 24;
    const int lb  = (bid >> 8) / 24;
    const int tid = threadIdx.x;

    // ---- zero the column-halo slots ----
    if (tid < 60) {
        int side = tid & 1;
        int row  = (tid >> 1) % 10;
        int a    = tid / 20;            // 0..2
        f16x8 z = {};
        *(f16x8*)&raw[a][row][side ? 200 : 0] = z;
    }

    // ---- stage A: coalesced strip loads (720 vector loads) ----
    for (int i = 0; i < 3; ++i) {
        int idx = tid + 256 * i;
        if (idx >= 720) break;
        int vec = idx % 24;
        int row = (idx / 24) % 10;
        int a   = idx / 240;            // 0..2
        int gh  = ph * 8 - 1 + row;
        f16x8 v = {};
        if (gh >= 0 && gh < HH) {
            const half_t* src;
            if (a == 0)      src = q1  + ((size_t)lb * 256 + c0) * HW;
            else if (a == 1) src = kv1 + ((size_t)lb * 512 + c0) * HW;
            else             src = kv1 + ((size_t)lb * 512 + 256 + c0) * HW;
            v = *(const f16x8*)&src[(size_t)gh * WW + vec * 8];
        }
        *(f16x8*)&raw[a][row][8 + vec * 8] = v;
    }
    __syncthreads();

    // ---- stage B: dwconv via dot2; u-fastest mapping, 288 units ----
    for (int i = 0; i < 2; ++i) {
        int unit = tid + 256 * i;
        if (unit >= 288) break;
        int u   = unit & 7;
        int xg2 = (unit >> 3) % 12;
        int a   = unit / 96;            // 0..2
        const half_t (*rw)[RS] = raw[a];
        const half_t* wt;
        float bias;
        if (a == 0)      { wt = qdw16 + (size_t)c0 * 9;         bias = qb[c0]; }
        else if (a == 1) { wt = kdw16 + (size_t)c0 * 9;         bias = kb[c0]; }
        else             { wt = kdw16 + (size_t)(256 + c0) * 9; bias = kb[256 + c0]; }
        u32 w01[3], w2z[3];
#pragma unroll
        for (int dy = 0; dy < 3; ++dy) {
            u32 a0 = (u32)__builtin_bit_cast(unsigned short, wt[dy * 3 + 0]);
            u32 a1 = (u32)__builtin_bit_cast(unsigned short, wt[dy * 3 + 1]);
            u32 a2 = (u32)__builtin_bit_cast(unsigned short, wt[dy * 3 + 2]);
            w01[dy] = a0 | (a1 << 16);
            w2z[dy] = a2;
        }
        const int x0 = xg2 * 16;
        float acc[16];
#pragma unroll
        for (int xx = 0; xx < 16; ++xx) acc[xx] = bias;
#pragma unroll
        for (int dy = 0; dy < 3; ++dy) {
            const half_t* rowp = &rw[u + dy][x0];
            uint4 c0v = *(const uint4*)(rowp);
            uint4 c1v = *(const uint4*)(rowp + 8);
            uint4 c2v = *(const uint4*)(rowp + 16);
            uint4 c3v = *(const uint4*)(rowp + 24);
            u32 H[13] = {c0v.x,c0v.y,c0v.z,c0v.w, c1v.x,c1v.y,c1v.z,c1v.w,
                         c2v.x,c2v.y,c2v.z,c2v.w, c3v.x};
            u32 A[12];
#pragma unroll
            for (int m = 3; m < 12; ++m) A[m] = (H[m] >> 16) | (H[m + 1] << 16);
#pragma unroll
            for (int xx = 0; xx < 16; ++xx) {
                u32 p01 = (xx & 1) ? H[(7 + xx) >> 1] : A[3 + (xx >> 1)];
                u32 p2  = (xx & 1) ? H[(9 + xx) >> 1] : A[4 + (xx >> 1)];
                acc[xx] = DOT2(p01, w01[dy], acc[xx]);
                acc[xx] = DOT2(p2,  w2z[dy], acc[xx]);
            }
        }
        f16x8 o0, o1;
#pragma unroll
        for (int xx = 0; xx < 8; ++xx) { o0[xx] = (half_t)acc[xx]; o1[xx] = (half_t)acc[8 + xx]; }
        if (a == 0) {
            *(f16x8*)&qd[u][x0]     = o0;
            *(f16x8*)&qd[u][x0 + 8] = o1;
        } else if (a == 1) {
            f16x8 r0v, r1v;
            r0v[0] = (half_t)acc[0];
            r1v[0] = (half_t)acc[8];
#pragma unroll
            for (int j = 1; j < 8; ++j) {
                r0v[j] = (half_t)acc[8 - j];
                r1v[j] = (half_t)acc[16 - j];
            }
            *(f16x8*)&krev[u][x0]     = r0v;
            *(f16x8*)&krev[u][x0 + 8] = r1v;
        } else {
            half_t* dst = &vd[((size_t)lb * 256 + c0) * HW + (size_t)(ph * 8 + u) * WW + x0];
            *(f16x8*)dst       = o0;
            *(f16x8*)(dst + 8) = o1;
        }
    }
    __syncthreads();

    // ---- stage C: circular conv via dot2, 192 units (tid<192) ----
    if (tid < 192) {
        int pw = tid >> 3;
        int u  = tid & 7;
        float acc[8];
#pragma unroll
        for (int v = 0; v < 8; ++v) acc[v] = 0.f;
#pragma unroll
        for (int s = 0; s < 8; ++s) {
            int r = (u - s) & 7;
            uint4 q4 = *(const uint4*)&qd[s][pw * 8];
            uint4 k4 = *(const uint4*)&krev[r][pw * 8];
            u32 Q[4] = {q4.x, q4.y, q4.z, q4.w};
            u32 K[4] = {k4.x, k4.y, k4.z, k4.w};
            u32 S[4];
#pragma unroll
            for (int m = 0; m < 4; ++m) S[m] = (K[m] >> 16) | (K[(m + 1) & 3] << 16);
#pragma unroll
            for (int v = 0; v < 8; ++v) {
                const int o = 8 - v;
#pragma unroll
                for (int tt = 0; tt < 4; ++tt) {
                    u32 pr = (o & 1) ? S[(((o - 1) >> 1) + tt) & 3]
                                     : K[((o >> 1) + tt) & 3];
                    acc[v] = DOT2(Q[tt], pr, acc[v]);
                }
            }
        }
        f16x8 ov;
#pragma unroll
        for (int v = 0; v < 8; ++v) ov[v] = (half_t)acc[v];
        *(f16x8*)&corr[((size_t)lb * 256 + c0) * HW + (size_t)(ph * 8 + u) * WW + pw * 8] = ov;
    }
}

// ---------------------------------------------------------------------------
// Fused LN(corr)*vd + 1x1 proj GEMM via MFMA 32x32x16 -> f32 out.
// Round-16/17 verified form. UNCHANGED.
// ---------------------------------------------------------------------------
__global__ __launch_bounds__(256)
void proj_kernel(const half_t* __restrict__ corr, const half_t* __restrict__ vd,
                 const float* __restrict__ lnw, const float* __restrict__ lnb,
                 const half_t* __restrict__ wp16, const float* __restrict__ wb,
                 float* __restrict__ out)
{
    __shared__ __attribute__((aligned(16))) char smem[SMEM_BYTES];
    half_t (*As)[136]  = (half_t(*)[136])smem;
    half_t (*Wsh)[136] = (half_t(*)[136])(smem + WSH_OFF);
    float  (*Cst)[68]  = (float (*)[68]) (smem + WSH_OFF);
    float* redA = (float*)(smem + WSH_OFF);           // [32][64] f32 = 8 KB
    float* redB = (float*)(smem + WSH_OFF + 8192);    // [32][64] f32 = 8 KB
    float* mu_s = (float*)(smem + MU_OFF);
    float* rs_s = mu_s + 64;

    const int tid  = threadIdx.x;
    const int l    = tid & 63;
    const int w    = tid >> 6;
    const int lrow = l & 31;
    const int lk   = (l >> 5) * 8;

    const long p0  = (long)blockIdx.x * 64;
    const int  lb  = (int)(p0 / HW);
    const int  hw0 = (int)(p0 - (long)lb * HW);

    // ---- LN stats (vectorized, corr cached in f16x8 registers) ----
    const int pxq8 = tid & 7;          // 8 px (f16x8)
    const int cg   = tid >> 3;         // 32 groups x 8 ch
    const half_t* cb = corr + (size_t)lb * 256 * HW + hw0 + pxq8 * 8;
    const half_t* vb = vd   + (size_t)lb * 256 * HW + hw0 + pxq8 * 8;

    f16x8 cpk[8];
    float s1[8], s2[8];
#pragma unroll
    for (int p = 0; p < 8; ++p) { s1[p] = 0.f; s2[p] = 0.f; }
#pragma unroll
    for (int j = 0; j < 8; ++j) {
        cpk[j] = *(const f16x8*)&cb[(size_t)(cg * 8 + j) * HW];
#pragma unroll
        for (int p = 0; p < 8; ++p) {
            float f = (float)cpk[j][p];
            s1[p] += f; s2[p] += f * f;
        }
    }
#pragma unroll
    for (int p = 0; p < 8; ++p) {
        redA[cg * 64 + pxq8 * 8 + p] = s1[p];
        redB[cg * 64 + pxq8 * 8 + p] = s2[p];
    }
    __syncthreads();
    if (tid < 64) {
        float su = 0.f, sq = 0.f;
#pragma unroll
        for (int c = 0; c < 32; ++c) { su += redA[c * 64 + tid]; sq += redB[c * 64 + tid]; }
        float mu  = su * (1.f / 256.f);
        float var = sq * (1.f / 256.f) - mu * mu;
        mu_s[tid] = mu;
        rs_s[tid] = rsqrtf(var + 1e-5f);
    }
    __syncthreads();

    f32x16 acc0, acc1;
#pragma unroll
    for (int i = 0; i < 16; ++i) { acc0[i] = 0.f; acc1[i] = 0.f; }

    for (int kc = 0; kc < 2; ++kc) {
        if (kc) __syncthreads();          // prior kc MFMA readers done with As
        if ((cg >> 4) == kc) {
            const int cgl = cg & 15;      // local channel group (0..15)
            float mu8[8], rs8[8];
#pragma unroll
            for (int p = 0; p < 8; ++p) {
                mu8[p] = mu_s[pxq8 * 8 + p];
                rs8[p] = rs_s[pxq8 * 8 + p];
            }
            f16x8 vvv[8];
            float lw[8], lbv[8];
#pragma unroll
            for (int j = 0; j < 8; ++j) {
                int c = kc * 128 + cgl * 8 + j;   // == cg*8 + j
                vvv[j] = *(const f16x8*)&vb[(size_t)c * HW];
                lw[j]  = lnw[c]; lbv[j] = lnb[c];
            }
#pragma unroll
            for (int p = 0; p < 8; ++p) {
                f16x8 o;
#pragma unroll
                for (int j = 0; j < 8; ++j) {
                    float cf = (float)cpk[j][p];
                    o[j] = (half_t)(((cf - mu8[p]) * rs8[p] * lw[j] + lbv[j]) * (float)vvv[j][p]);
                }
                *(f16x8*)&As[pxq8 * 8 + p][cgl * 8] = o;
            }
        }
#pragma unroll
        for (int i = 0; i < 8; ++i) {
            int f  = i * 256 + tid;
            int n  = f >> 4;
            int xh = (f & 15) * 8;
            *(f16x8*)&Wsh[n][xh] = *(const f16x8*)&wp16[(size_t)n * 256 + kc * 128 + xh];
        }
        __syncthreads();

        f16x8 af[8];
#pragma unroll
        for (int kk = 0; kk < 8; ++kk)
            af[kk] = *(const f16x8*)&Wsh[w * 32 + lrow][kk * 16 + lk];
#pragma unroll
        for (int kk = 0; kk < 8; ++kk) {
            f16x8 b0 = *(const f16x8*)&As[lrow][kk * 16 + lk];
            f16x8 b1 = *(const f16x8*)&As[32 + lrow][kk * 16 + lk];
            acc0 = __builtin_amdgcn_mfma_f32_32x32x16_f16(af[kk], b0, acc0, 0, 0, 0);
            acc1 = __builtin_amdgcn_mfma_f32_32x32x16_f16(af[kk], b1, acc1, 0, 0, 0);
        }
    }
    __syncthreads();

#pragma unroll
    for (int r = 0; r < 16; ++r) {
        int oc = w * 32 + (r & 3) + 8 * (r >> 2) + 4 * (l >> 5);
        Cst[oc][lrow]      = acc0[r];
        Cst[oc][32 + lrow] = acc1[r];
    }
    __syncthreads();

#pragma unroll
    for (int i = 0; i < 8; ++i) {
        int idx = i * 256 + tid;          // 2048 float4 stores
        int oc  = idx >> 4;
        int pxq = idx & 15;
        float4 a = *(const float4*)&Cst[oc][pxq * 4];
        float bias = wb[oc];
        a.x += bias; a.y += bias; a.z += bias; a.w += bias;
        *(float4*)&out[((size_t)lb * 128 + oc) * HW + hw0 + pxq * 4] = a;
    }
}

// ---------------------------------------------------------------------------
extern "C" void kernel_launch(void* const* d_in, const int* in_sizes, int n_in,
                              void* d_out, int out_size, void* d_ws, size_t ws_size,
                              hipStream_t stream)
{
    const float* x        = (const float*)d_in[0];
    const float* evt      = (const float*)d_in[1];
    const float* ln_img_w = (const float*)d_in[2];
    const float* ln_img_b = (const float*)d_in[3];
    const float* ln_evt_w = (const float*)d_in[4];
    const float* ln_evt_b = (const float*)d_in[5];
    const float* q_w      = (const float*)d_in[6];
    const float* q_b      = (const float*)d_in[7];
    const float* q_dw_w   = (const float*)d_in[8];
    const float* q_dw_b   = (const float*)d_in[9];
    const float* kv_w     = (const float*)d_in[10];
    const float* kv_b     = (const float*)d_in[11];
    const float* kv_dw_w  = (const float*)d_in[12];
    const float* kv_dw_b  = (const float*)d_in[13];
    const float* ln_corr_w= (const float*)d_in[14];
    const float* ln_corr_b= (const float*)d_in[15];
    const float* proj_w   = (const float*)d_in[16];
    const float* proj_b   = (const float*)d_in[17];
    float* out = (float*)d_out;

    // f16 weight cache at the tail of ws (137984 halfs = 276 KB)
    const size_t wtail = (ws_size - 278528) & ~(size_t)255;
    half_t* wf    = (half_t*)((char*)d_ws + wtail);
    half_t* wq16  = wf;             // 256x128
    half_t* wkv16 = wf + 32768;     // 512x128
    half_t* wp16  = wf + 98304;     // 128x256
    half_t* qdw16 = wf + 131072;    // 256x9
    half_t* kdw16 = wf + 133376;    // 512x9

    const size_t per_b = (size_t)(256 + 512 + 256 + 256) * HW * sizeof(half_t); // 94.4 MB
    int PB = 1;
    if      (wtail >= 8 * per_b) PB = 8;
    else if (wtail >= 4 * per_b) PB = 4;
    else if (wtail >= 2 * per_b) PB = 2;

    half_t* q1   = (half_t*)d_ws;
    half_t* kv1  = q1  + (size_t)PB * 256 * HW;
    half_t* vd   = kv1 + (size_t)PB * 512 * HW;
    half_t* corr = vd  + (size_t)PB * 256 * HW;

    dim3 blk(256);
    wcvt_kernel<<<135, blk, 0, stream>>>(q_w, kv_w, proj_w, q_dw_w, kv_dw_w, wf);

    for (int b0 = 0; b0 < BATCH; b0 += PB) {
        int nb = PB;
        ln_gemm_kernel<256><<<nb * PXB, blk, 0, stream>>>(
            x + (size_t)b0 * CIN * HW, ln_img_w, ln_img_b, wq16, q_b, q1);
        ln_gemm_kernel<512><<<nb * PXB, blk, 0, stream>>>(
            evt + (size_t)b0 * CIN * HW, ln_evt_w, ln_evt_b, wkv16, kv_b, kv1);
        corr_strip_kernel<<<nb * 24 * 256, blk, 0, stream>>>(
            q1, kv1, qdw16, q_dw_b, kdw16, kv_dw_b, corr, vd);
        proj_kernel<<<nb * PXB, blk, 0, stream>>>(
            corr, vd, ln_corr_w, ln_corr_b, wp16, proj_b,
            out + (size_t)b0 * 128 * HW);
    }
}